// Round 1
// baseline (304.547 us; speedup 1.0000x reference)
//
#include <hip/hip_runtime.h>
#include <hip/hip_bf16.h>

#define N_ROWS 8192
#define DIM 1024
#define TEMP_INV (1.0f / 0.07f)

typedef __attribute__((ext_vector_type(8))) __bf16 bf16x8;
typedef __attribute__((ext_vector_type(4))) float f32x4;

__device__ inline void gload_lds16(const __hip_bfloat16* g, __hip_bfloat16* l) {
    __builtin_amdgcn_global_load_lds(
        (const __attribute__((address_space(1))) void*)g,
        (__attribute__((address_space(3))) void*)l,
        16, 0, 0);
}

// ---------------- Kernel 1: L2-normalize rows, write bf16 ----------------
__global__ __launch_bounds__(256) void knorm(const float* __restrict__ X,
                                             __hip_bfloat16* __restrict__ Y) {
    const int row = blockIdx.x;
    const int t = threadIdx.x;
    const float* x = X + (size_t)row * DIM;
    float4 v = reinterpret_cast<const float4*>(x)[t];
    float ss = v.x * v.x + v.y * v.y + v.z * v.z + v.w * v.w;
    #pragma unroll
    for (int off = 32; off > 0; off >>= 1) ss += __shfl_down(ss, off);
    __shared__ float red[4];
    if ((t & 63) == 0) red[t >> 6] = ss;
    __syncthreads();
    float tot = red[0] + red[1] + red[2] + red[3];
    float inv = 1.0f / fmaxf(sqrtf(tot), 1e-12f);
    __hip_bfloat16 o[4];
    o[0] = __float2bfloat16(v.x * inv);
    o[1] = __float2bfloat16(v.y * inv);
    o[2] = __float2bfloat16(v.z * inv);
    o[3] = __float2bfloat16(v.w * inv);
    reinterpret_cast<ushort4*>(Y + (size_t)row * DIM)[t] =
        *reinterpret_cast<ushort4*>(o);
}

// ---------------- Kernel 2: fused GEMM (f f^T) + streaming row reduce ----
// 128x128 tile, BK=32, 256 threads = 4 waves (2x2), each wave 64x64 via
// 4x4 fragments of mfma_f32_16x16x32_bf16.
__global__ __launch_bounds__(256) void kgemm(const __hip_bfloat16* __restrict__ F,
                                             const int* __restrict__ labels,
                                             float* __restrict__ S1,
                                             float* __restrict__ S2,
                                             float* __restrict__ CNT) {
    constexpr int BM = 128, BN = 128, BK = 32;
    __shared__ __align__(16) __hip_bfloat16 As[BM * BK];
    __shared__ __align__(16) __hip_bfloat16 Bs[BN * BK];
    __shared__ int labR[BM];
    __shared__ int labC[BN];

    const int bid = blockIdx.x;
    const int bx = bid & 63;      // col tile
    const int by = bid >> 6;      // row tile
    const int rowBase = by * BM;
    const int colBase = bx * BN;

    const int t = threadIdx.x;
    const int lane = t & 63;
    const int wid = t >> 6;       // 0..3
    const int wr = wid >> 1;      // wave row (0/1)
    const int wc = wid & 1;       // wave col (0/1)
    const int l16 = lane & 15;
    const int g16 = lane >> 4;    // 0..3

    if (t < 128) labR[t] = labels[rowBase + t];
    else         labC[t - 128] = labels[colBase + (t - 128)];

    f32x4 acc[4][4];
    #pragma unroll
    for (int m = 0; m < 4; ++m)
        #pragma unroll
        for (int n = 0; n < 4; ++n)
            acc[m][n] = f32x4{0.f, 0.f, 0.f, 0.f};

    const int srow = t >> 2;          // 0..63
    const int scol = (t & 3) * 8;     // 0/8/16/24

    for (int kt = 0; kt < DIM / BK; ++kt) {
        const int k0 = kt * BK;
        #pragma unroll
        for (int i = 0; i < 2; ++i) {
            const int r = i * 64 + srow;
            gload_lds16(F + (size_t)(rowBase + r) * DIM + k0 + scol, &As[r * BK + scol]);
            gload_lds16(F + (size_t)(colBase + r) * DIM + k0 + scol, &Bs[r * BK + scol]);
        }
        __syncthreads();

        bf16x8 a[4], b[4];
        #pragma unroll
        for (int m = 0; m < 4; ++m)
            a[m] = *reinterpret_cast<const bf16x8*>(&As[(wr * 64 + m * 16 + l16) * BK + g16 * 8]);
        #pragma unroll
        for (int n = 0; n < 4; ++n)
            b[n] = *reinterpret_cast<const bf16x8*>(&Bs[(wc * 64 + n * 16 + l16) * BK + g16 * 8]);
        #pragma unroll
        for (int m = 0; m < 4; ++m)
            #pragma unroll
            for (int n = 0; n < 4; ++n)
                acc[m][n] = __builtin_amdgcn_mfma_f32_16x16x32_bf16(a[m], b[n], acc[m][n], 0, 0, 0);
        __syncthreads();
    }

    // Epilogue: per-row streaming reduction.
    // C/D layout: col = colBase + wc*64 + n*16 + (lane&15)
    //             row = rowBase + wr*64 + m*16 + (lane>>4)*4 + reg
    int labCn[4];
    #pragma unroll
    for (int n = 0; n < 4; ++n) labCn[n] = labC[wc * 64 + n * 16 + l16];

    #pragma unroll
    for (int m = 0; m < 4; ++m) {
        const int rloc = wr * 64 + m * 16 + g16 * 4;
        #pragma unroll
        for (int reg = 0; reg < 4; ++reg) {
            const int row = rowBase + rloc + reg;
            const int labRow = labR[rloc + reg];
            float e = 0.f, s2 = 0.f, c = 0.f;
            #pragma unroll
            for (int n = 0; n < 4; ++n) {
                const float sim = acc[m][n][reg] * TEMP_INV;
                const int col = colBase + wc * 64 + n * 16 + l16;
                if (row != col) e += __expf(sim);
                if (labRow == labCn[n]) { s2 += sim; c += 1.0f; }
            }
            #pragma unroll
            for (int off = 1; off < 16; off <<= 1) {
                e  += __shfl_xor(e, off);
                s2 += __shfl_xor(s2, off);
                c  += __shfl_xor(c, off);
            }
            if (l16 == 0) {
                atomicAdd(&S1[row], e);
                atomicAdd(&S2[row], s2);
                atomicAdd(&CNT[row], c);
            }
        }
    }
}

// ---------------- Kernel 3: finalize ----------------
__global__ __launch_bounds__(256) void kfinal(const float* __restrict__ S1,
                                              const float* __restrict__ S2,
                                              const float* __restrict__ CNT,
                                              float* __restrict__ out) {
    const int t = threadIdx.x;
    float a = 0.f;
    for (int i = t; i < N_ROWS; i += 256) {
        const float cnt = CNT[i];
        const float ld = logf(S1[i] + 1e-12f);
        a += (cnt * ld - S2[i]) / (cnt + 1e-12f);
    }
    #pragma unroll
    for (int off = 32; off > 0; off >>= 1) a += __shfl_down(a, off);
    __shared__ float red[4];
    if ((t & 63) == 0) red[t >> 6] = a;
    __syncthreads();
    if (t == 0) out[0] = (red[0] + red[1] + red[2] + red[3]) / (float)N_ROWS;
}

extern "C" void kernel_launch(void* const* d_in, const int* in_sizes, int n_in,
                              void* d_out, int out_size, void* d_ws, size_t ws_size,
                              hipStream_t stream) {
    const float* feat = (const float*)d_in[0];
    const int* labels = (const int*)d_in[1];
    float* out = (float*)d_out;

    __hip_bfloat16* Fn = (__hip_bfloat16*)d_ws;
    float* S1 = (float*)((char*)d_ws + (size_t)N_ROWS * DIM * 2);
    float* S2 = S1 + N_ROWS;
    float* CNT = S2 + N_ROWS;

    hipMemsetAsync(S1, 0, 3 * N_ROWS * sizeof(float), stream);
    knorm<<<N_ROWS, 256, 0, stream>>>(feat, Fn);
    kgemm<<<(N_ROWS / 128) * (N_ROWS / 128), 256, 0, stream>>>(Fn, labels, S1, S2, CNT);
    kfinal<<<1, 256, 0, stream>>>(S1, S2, CNT, out);
}

// Round 2
// 155.003 us; speedup vs baseline: 1.9648x; 1.9648x over previous
//
#include <hip/hip_runtime.h>
#include <hip/hip_bf16.h>

#define N_ROWS 8192
#define DIM 1024
#define TEMP_INV (1.0f / 0.07f)

typedef __attribute__((ext_vector_type(8))) __bf16 bf16x8;
typedef __attribute__((ext_vector_type(4))) float f32x4;

__device__ inline void gload_lds16(const __hip_bfloat16* g, __hip_bfloat16* l) {
    __builtin_amdgcn_global_load_lds(
        (const __attribute__((address_space(1))) void*)g,
        (__attribute__((address_space(3))) void*)l,
        16, 0, 0);
}

// ---------------- Kernel 1: L2-normalize rows, write bf16 ----------------
__global__ __launch_bounds__(256) void knorm(const float* __restrict__ X,
                                             __hip_bfloat16* __restrict__ Y) {
    const int row = blockIdx.x;
    const int t = threadIdx.x;
    const float* x = X + (size_t)row * DIM;
    float4 v = reinterpret_cast<const float4*>(x)[t];
    float ss = v.x * v.x + v.y * v.y + v.z * v.z + v.w * v.w;
    #pragma unroll
    for (int off = 32; off > 0; off >>= 1) ss += __shfl_down(ss, off);
    __shared__ float red[4];
    if ((t & 63) == 0) red[t >> 6] = ss;
    __syncthreads();
    float tot = red[0] + red[1] + red[2] + red[3];
    float inv = 1.0f / fmaxf(sqrtf(tot), 1e-12f);
    __hip_bfloat16 o[4];
    o[0] = __float2bfloat16(v.x * inv);
    o[1] = __float2bfloat16(v.y * inv);
    o[2] = __float2bfloat16(v.z * inv);
    o[3] = __float2bfloat16(v.w * inv);
    reinterpret_cast<ushort4*>(Y + (size_t)row * DIM)[t] =
        *reinterpret_cast<ushort4*>(o);
}

// ---------------- Kernel 2: fused GEMM (f f^T) + streaming reductions ----
// Triangular grid: only tiles (by,bx) with bx >= by. Off-diagonal tiles
// contribute BOTH a row-direction reduction (rows of by-block) and a
// col-direction reduction (rows of bx-block), exploiting sim symmetry.
// 128x128 tile, BK=32, 256 threads = 4 waves (2x2), each wave 64x64 via
// 4x4 fragments of mfma_f32_16x16x32_bf16.
__global__ __launch_bounds__(256) void kgemm(const __hip_bfloat16* __restrict__ F,
                                             const int* __restrict__ labels,
                                             float* __restrict__ S1,
                                             float* __restrict__ S2,
                                             float* __restrict__ CNT) {
    constexpr int BM = 128, BN = 128, BK = 32;
    __shared__ __align__(16) __hip_bfloat16 As[BM * BK];
    __shared__ __align__(16) __hip_bfloat16 Bs[BN * BK];
    __shared__ int labR[BM];
    __shared__ int labC[BN];

    // map blockIdx.x -> lower-triangular pair (a,b), a>=b; by=b, bx=a
    const int bid = blockIdx.x;
    int a = (int)((sqrtf(8.0f * (float)bid + 1.0f) - 1.0f) * 0.5f);
    while ((a + 1) * (a + 2) / 2 <= bid) ++a;
    while (a * (a + 1) / 2 > bid) --a;
    const int bx = a;                      // col tile (>= by)
    const int by = bid - a * (a + 1) / 2;  // row tile
    const bool diag = (bx == by);
    const int rowBase = by * BM;
    const int colBase = bx * BN;

    const int t = threadIdx.x;
    const int lane = t & 63;
    const int wid = t >> 6;       // 0..3
    const int wr = wid >> 1;      // wave row (0/1)
    const int wc = wid & 1;       // wave col (0/1)
    const int l16 = lane & 15;
    const int g16 = lane >> 4;    // 0..3

    if (t < 128) labR[t] = labels[rowBase + t];
    else         labC[t - 128] = labels[colBase + (t - 128)];

    f32x4 acc[4][4];
    #pragma unroll
    for (int m = 0; m < 4; ++m)
        #pragma unroll
        for (int n = 0; n < 4; ++n)
            acc[m][n] = f32x4{0.f, 0.f, 0.f, 0.f};

    const int srow = t >> 2;          // 0..63
    const int scol = (t & 3) * 8;     // 0/8/16/24

    for (int kt = 0; kt < DIM / BK; ++kt) {
        const int k0 = kt * BK;
        #pragma unroll
        for (int i = 0; i < 2; ++i) {
            const int r = i * 64 + srow;
            gload_lds16(F + (size_t)(rowBase + r) * DIM + k0 + scol, &As[r * BK + scol]);
            gload_lds16(F + (size_t)(colBase + r) * DIM + k0 + scol, &Bs[r * BK + scol]);
        }
        __syncthreads();

        bf16x8 av[4], bv[4];
        #pragma unroll
        for (int m = 0; m < 4; ++m)
            av[m] = *reinterpret_cast<const bf16x8*>(&As[(wr * 64 + m * 16 + l16) * BK + g16 * 8]);
        #pragma unroll
        for (int n = 0; n < 4; ++n)
            bv[n] = *reinterpret_cast<const bf16x8*>(&Bs[(wc * 64 + n * 16 + l16) * BK + g16 * 8]);
        #pragma unroll
        for (int m = 0; m < 4; ++m)
            #pragma unroll
            for (int n = 0; n < 4; ++n)
                acc[m][n] = __builtin_amdgcn_mfma_f32_16x16x32_bf16(av[m], bv[n], acc[m][n], 0, 0, 0);
        __syncthreads();
    }

    // Epilogue. C/D layout:
    //   col = colBase + wc*64 + n*16 + (lane&15)
    //   row = rowBase + wr*64 + m*16 + (lane>>4)*4 + reg
    int labCn[4];
    #pragma unroll
    for (int n = 0; n < 4; ++n) labCn[n] = labC[wc * 64 + n * 16 + l16];

    float colE[4]  = {0.f, 0.f, 0.f, 0.f};
    float colS2[4] = {0.f, 0.f, 0.f, 0.f};
    float colC[4]  = {0.f, 0.f, 0.f, 0.f};

    #pragma unroll
    for (int m = 0; m < 4; ++m) {
        const int rloc = wr * 64 + m * 16 + g16 * 4;
        #pragma unroll
        for (int reg = 0; reg < 4; ++reg) {
            const int row = rowBase + rloc + reg;
            const int labRow = labR[rloc + reg];
            float e = 0.f, s2 = 0.f, c = 0.f;
            #pragma unroll
            for (int n = 0; n < 4; ++n) {
                const float sim = acc[m][n][reg] * TEMP_INV;
                const int col = colBase + wc * 64 + n * 16 + l16;
                const float ex = __expf(sim);
                const bool same = (labRow == labCn[n]);
                if (diag) {
                    if (row != col) e += ex;
                } else {
                    e += ex;
                    colE[n] += ex;
                }
                if (same) {
                    s2 += sim; c += 1.0f;
                    if (!diag) { colS2[n] += sim; colC[n] += 1.0f; }
                }
            }
            #pragma unroll
            for (int off = 1; off < 16; off <<= 1) {
                e  += __shfl_xor(e, off);
                s2 += __shfl_xor(s2, off);
                c  += __shfl_xor(c, off);
            }
            if (l16 == 0) {
                atomicAdd(&S1[row], e);
                atomicAdd(&S2[row], s2);
                atomicAdd(&CNT[row], c);
            }
        }
    }

    // Column-direction reduction for off-diagonal tiles (symmetry).
    if (!diag) {
        #pragma unroll
        for (int n = 0; n < 4; ++n) {
            float ce = colE[n], cs = colS2[n], cc = colC[n];
            #pragma unroll
            for (int off = 16; off < 64; off <<= 1) {
                ce += __shfl_xor(ce, off);
                cs += __shfl_xor(cs, off);
                cc += __shfl_xor(cc, off);
            }
            if (g16 == 0) {
                const int col = colBase + wc * 64 + n * 16 + l16;
                atomicAdd(&S1[col], ce);
                atomicAdd(&S2[col], cs);
                atomicAdd(&CNT[col], cc);
            }
        }
    }
}

// ---------------- Kernel 3: finalize ----------------
__global__ __launch_bounds__(256) void kfinal(const float* __restrict__ S1,
                                              const float* __restrict__ S2,
                                              const float* __restrict__ CNT,
                                              float* __restrict__ out) {
    const int t = threadIdx.x;
    float a = 0.f;
    for (int i = t; i < N_ROWS; i += 256) {
        const float cnt = CNT[i];
        const float ld = logf(S1[i] + 1e-12f);
        a += (cnt * ld - S2[i]) / (cnt + 1e-12f);
    }
    #pragma unroll
    for (int off = 32; off > 0; off >>= 1) a += __shfl_down(a, off);
    __shared__ float red[4];
    if ((t & 63) == 0) red[t >> 6] = a;
    __syncthreads();
    if (t == 0) out[0] = (red[0] + red[1] + red[2] + red[3]) / (float)N_ROWS;
}

extern "C" void kernel_launch(void* const* d_in, const int* in_sizes, int n_in,
                              void* d_out, int out_size, void* d_ws, size_t ws_size,
                              hipStream_t stream) {
    const float* feat = (const float*)d_in[0];
    const int* labels = (const int*)d_in[1];
    float* out = (float*)d_out;

    __hip_bfloat16* Fn = (__hip_bfloat16*)d_ws;
    float* S1 = (float*)((char*)d_ws + (size_t)N_ROWS * DIM * 2);
    float* S2 = S1 + N_ROWS;
    float* CNT = S2 + N_ROWS;

    constexpr int NT = N_ROWS / 128;              // 64 tiles per dim
    constexpr int NBLK = NT * (NT + 1) / 2;       // 2080 triangular blocks

    hipMemsetAsync(S1, 0, 3 * N_ROWS * sizeof(float), stream);
    knorm<<<N_ROWS, 256, 0, stream>>>(feat, Fn);
    kgemm<<<NBLK, 256, 0, stream>>>(Fn, labels, S1, S2, CNT);
    kfinal<<<1, 256, 0, stream>>>(S1, S2, CNT, out);
}